// Round 6
// baseline (60.879 us; speedup 1.0000x reference)
//
#include <hip/hip_runtime.h>
#include <math.h>

#define NN 2048
#define DD 16
#define HH 128
#define EPSF 1e-10f
#define PIO2 1.57079632679489662f

// ---------------- workspace float layout ----------------
#define SC    0      // 8 scalars: [2]=lossOverlap, [3]=sum_r2, [4]=sum_o2
#define PEX   8      // 128 per-block partial lossExceed
#define PSH   136    // 128 per-block partial lossShapeLike
#define PCSD  264    // 128*16 per-block partial colsumDiff
#define CSR   2312   // colsum_r[2048]
#define CSO   4360   // colsum_o[2048]
#define SQ    6408   // sq[2048]
#define CLG   8456   // gathered lower [N*16]
#define CHG   (CLG + NN*DD)          // 41224
#define OMB   (CHG + NN*DD)          // 73992: omega bf16 copy (2048*128 bf16)
#define OMB_B (OMB * 4)              // byte offset, 16B aligned

typedef __attribute__((ext_vector_type(8)))  short  bf16x8;
typedef __attribute__((ext_vector_type(16))) float  f32x16;

__device__ __forceinline__ float waveReduce(float v) {
    #pragma unroll
    for (int o = 32; o > 0; o >>= 1) v += __shfl_down(v, o, 64);
    return v;
}

__device__ __forceinline__ unsigned int bf16rne(float x) {
    unsigned int u = __float_as_uint(x);
    u += 0x7fff + ((u >> 16) & 1);
    return u >> 16;
}
__device__ __forceinline__ unsigned int pkbf(float a, float b) {
    return bf16rne(a) | (bf16rne(b) << 16);
}

// ---------------- kernel A: gather + elementwise + sq + bf16 convert + zeroing ----
__global__ __launch_bounds__(256) void k_setup(
    const int* __restrict__ idx, const float* __restrict__ omega,
    const float* __restrict__ chL, const float* __restrict__ chH,
    const float* __restrict__ pL, const float* __restrict__ pH,
    const float* __restrict__ pR, const float* __restrict__ lr,
    float* __restrict__ ws)
{
    int t = threadIdx.x, b = blockIdx.x;
    int g = b * 256 + t;
    int i = g >> 4, d = g & 15;
    int id = idx[i];

    float c0 = chL[id * DD + d];
    float c1 = chH[id * DD + d];
    ws[CLG + i * DD + d] = c0;
    ws[CHG + i * DD + d] = c1;

    if (t < 16) { ws[CSR + b * 16 + t] = 0.f; ws[CSO + b * 16 + t] = 0.f; }
    if (b == 0 && t >= 16 && t < 24) ws[SC + (t - 16)] = 0.f;

    float l = pL[d], h = pH[d], r = pR[d];
    float ex = fmaxf(l - c0, 0.f) + fmaxf(c1 - h, 0.f)
             + fmaxf(l - c1, 0.f) + fmaxf(c0 - h, 0.f);
    float diff = c1 - c0;
    float denom = lr[id];
    float numer = fmaxf(diff / r, EPSF);
    float sdiv = fminf(fmaxf(numer / denom, 0.01f), 1.99f);
    float sh = fabsf(tanf((sdiv - 1.0f) * PIO2));

    const float4* op = (const float4*)(omega + i * HH + d * 8);
    float4 v0 = op[0], v1 = op[1];
    float s = v0.x*v0.x + v0.y*v0.y + v0.z*v0.z + v0.w*v0.w
            + v1.x*v1.x + v1.y*v1.y + v1.z*v1.z + v1.w*v1.w;
    *(uint4*)((char*)ws + OMB_B + i * 256 + d * 16) =
        make_uint4(pkbf(v0.x, v0.y), pkbf(v0.z, v0.w), pkbf(v1.x, v1.y), pkbf(v1.z, v1.w));
    s += __shfl_xor(s, 1, 64);
    s += __shfl_xor(s, 2, 64);
    s += __shfl_xor(s, 4, 64);
    s += __shfl_xor(s, 8, 64);
    if (d == 0) ws[SQ + i] = s;

    float dsw = diff;
    dsw += __shfl_xor(dsw, 16, 64);
    dsw += __shfl_xor(dsw, 32, 64);

    __shared__ float scol[16], pex[4], psh[4];
    if (t < 16) scol[t] = 0.f;
    __syncthreads();
    if ((t & 63) < 16) atomicAdd(&scol[t & 15], dsw);
    float exw = waveReduce(ex), shw = waveReduce(sh);
    if ((t & 63) == 0) { pex[t >> 6] = exw; psh[t >> 6] = shw; }
    __syncthreads();
    if (t < 16) ws[PCSD + b * 16 + t] = scol[t];
    if (t == 0) {
        ws[PEX + b] = pex[0] + pex[1] + pex[2] + pex[3];
        ws[PSH + b] = psh[0] + psh[1] + psh[2] + psh[3];
    }
}

// ---------------- kernel B1: box pairwise, 64-i x 128-j tiles ----------------
// 512 blocks: 32 i-tiles x 16 j-tiles. LDS ~8.7 KB.
__global__ __launch_bounds__(256) void k_box(float* __restrict__ ws)
{
    __shared__ __align__(16) float sCl[64 * DD];
    __shared__ __align__(16) float sCh[64 * DD];
    __shared__ float scol[128];
    __shared__ float boxp[8];
    int t = threadIdx.x;
    int b = blockIdx.x;
    int it = b >> 4;       // 32 i-tiles of 64
    int jt = b & 15;       // 16 j-tiles of 128

    ((float4*)sCl)[t] = ((const float4*)(ws + CLG + it * 64 * DD))[t];
    ((float4*)sCh)[t] = ((const float4*)(ws + CHG + it * 64 * DD))[t];
    if (t < 128) scol[t] = 0.f;

    int jl = t & 63;
    int j0 = jt * 128 + jl, j1 = j0 + 64;
    float4 l0[4], h0[4], l1[4], h1[4];
    #pragma unroll
    for (int q = 0; q < 4; q++) {
        l0[q] = ((const float4*)(ws + CLG + j0 * DD))[q];
        h0[q] = ((const float4*)(ws + CHG + j0 * DD))[q];
        l1[q] = ((const float4*)(ws + CLG + j1 * DD))[q];
        h1[q] = ((const float4*)(ws + CHG + j1 * DD))[q];
    }
    __syncthreads();

    int isub = t >> 6;   // wave-uniform i-subset
    float ca0 = 0.f, ca1 = 0.f, ov = 0.f, r2 = 0.f;
    #pragma unroll 4
    for (int ii = 0; ii < 16; ii++) {
        int il = isub * 16 + ii;
        int ig = it * 64 + il;
        float r0 = 0.f, o0 = 0.f, r1 = 0.f, o1 = 0.f;
        #pragma unroll
        for (int q = 0; q < 4; q++) {
            float4 li = ((const float4*)(sCl + il * DD))[q];   // broadcast
            float4 hi = ((const float4*)(sCh + il * DD))[q];
            r0 += fabsf(l0[q].x - li.x) + fabsf(l0[q].y - li.y)
                + fabsf(l0[q].z - li.z) + fabsf(l0[q].w - li.w);
            o0 += fmaxf(fminf(h0[q].x, hi.x) - fmaxf(l0[q].x, li.x), 0.f)
                + fmaxf(fminf(h0[q].y, hi.y) - fmaxf(l0[q].y, li.y), 0.f)
                + fmaxf(fminf(h0[q].z, hi.z) - fmaxf(l0[q].z, li.z), 0.f)
                + fmaxf(fminf(h0[q].w, hi.w) - fmaxf(l0[q].w, li.w), 0.f);
            r1 += fabsf(l1[q].x - li.x) + fabsf(l1[q].y - li.y)
                + fabsf(l1[q].z - li.z) + fabsf(l1[q].w - li.w);
            o1 += fmaxf(fminf(h1[q].x, hi.x) - fmaxf(l1[q].x, li.x), 0.f)
                + fmaxf(fminf(h1[q].y, hi.y) - fmaxf(l1[q].y, li.y), 0.f)
                + fmaxf(fminf(h1[q].z, hi.z) - fmaxf(l1[q].z, li.z), 0.f)
                + fmaxf(fminf(h1[q].w, hi.w) - fmaxf(l1[q].w, li.w), 0.f);
        }
        if (ig != j0) ov += o0;
        if (ig != j1) ov += o1;
        ca0 += r0;
        ca1 += r1;
        r2 = fmaf(r0, r0, fmaf(r1, r1, r2));
    }
    atomicAdd(&scol[jl], ca0);
    atomicAdd(&scol[jl + 64], ca1);
    float ovW = waveReduce(ov), r2W = waveReduce(r2);
    int w = t >> 6;
    if ((t & 63) == 0) { boxp[w] = ovW; boxp[4 + w] = r2W; }
    __syncthreads();
    if (t < 128) atomicAdd(&ws[CSR + jt * 128 + t], scol[t]);
    if (t == 0) {
        atomicAdd(&ws[SC + 2], boxp[0] + boxp[1] + boxp[2] + boxp[3]);
        atomicAdd(&ws[SC + 3], boxp[4] + boxp[5] + boxp[6] + boxp[7]);
    }
}

// ---------------- kernel B2: omega Gram, 64x64 tiles, K-split staging ----------
// 1024 blocks. LDS 17.2 KB -> ~9 blocks/CU capacity.
__global__ __launch_bounds__(256) void k_gram(float* __restrict__ ws)
{
    __shared__ __align__(16) char smem[17168];
    int t = threadIdx.x;
    int b = blockIdx.x;
    int i0 = (b >> 5) * 64, j0 = (b & 31) * 64;
    const char* wsb = (const char*)ws;

    float* sqA  = (float*)(smem + 16384);
    float* sqB  = (float*)(smem + 16640);
    float* cols = (float*)(smem + 16896);
    float* osum = (float*)(smem + 17152);
    if (t < 64) sqA[t] = ws[SQ + i0 + t];
    else if (t < 128) sqB[t - 64] = ws[SQ + j0 + (t - 64)];
    else if (t < 192) cols[t - 128] = 0.f;

    int w = t >> 6, l = t & 63;
    int rh = w >> 1, qc = w & 1, kh = l >> 5;
    int rowA = rh * 32 + (l & 31);
    int rowB = qc * 32 + (l & 31);
    f32x16 acc;
    #pragma unroll
    for (int m = 0; m < 16; m++) acc[m] = 0.f;

    // two K-halves of 64 through one 2x8KB buffer
    #pragma unroll
    for (int h = 0; h < 2; h++) {
        #pragma unroll
        for (int k = 0; k < 2; k++) {
            int x = t + k * 256;
            int r = x >> 3, c = x & 7;
            int sc = (h * 8 + (c ^ (r & 7))) * 16;   // pre-swizzled source
            *(uint4*)(smem + r * 128 + c * 16) =
                *(const uint4*)(wsb + OMB_B + (i0 + r) * 256 + sc);
            *(uint4*)(smem + 8192 + r * 128 + c * 16) =
                *(const uint4*)(wsb + OMB_B + (j0 + r) * 256 + sc);
        }
        __syncthreads();
        #pragma unroll
        for (int s = 0; s < 4; s++) {
            int ca = ((2 * s + kh) ^ (rowA & 7)) * 16;
            int cb = ((2 * s + kh) ^ (rowB & 7)) * 16;
            bf16x8 af = *(const bf16x8*)(smem + rowA * 128 + ca);
            bf16x8 bf = *(const bf16x8*)(smem + 8192 + rowB * 128 + cb);
            acc = __builtin_amdgcn_mfma_f32_32x32x16_bf16(af, bf, acc, 0, 0, 0);
        }
        __syncthreads();
    }

    float sqj = sqB[rowB];
    float o2 = 0.f, colv = 0.f;
    #pragma unroll
    for (int m = 0; m < 16; m++) {
        int row = (m & 3) + 8 * (m >> 2) + 4 * kh;   // validated C layout
        float o = fmaxf(sqA[rh * 32 + row] + sqj - 2.0f * acc[m], EPSF);
        o2 = fmaf(o, o, o2);
        colv += o;
    }
    atomicAdd(&cols[qc * 32 + (l & 31)], colv);
    o2 = waveReduce(o2);
    if (l == 0) osum[w] = o2;
    __syncthreads();
    if (t < 64) atomicAdd(&ws[CSO + j0 + t], cols[t]);
    if (t == 0) atomicAdd(&ws[SC + 4], osum[0] + osum[1] + osum[2] + osum[3]);
}

// ---------------- kernel C: finalize ----------------
__global__ __launch_bounds__(256) void k_final(
    const float* __restrict__ pR, float* __restrict__ ws, float* __restrict__ out)
{
    int t = threadIdx.x;
    __shared__ float scol[16], red[16];
    float sum_r2 = ws[SC + 3], sum_o2 = ws[SC + 4];
    float nr = fmaxf(sqrtf(sum_r2), EPSF);
    float no = fmaxf(sqrtf(sum_o2), EPSF);

    float s_dn2 = 0.f, s_cross = 0.f;
    for (int j = t; j < NN; j += 256) {
        float dn = ws[CSR + j] / nr;
        s_dn2 = fmaf(dn, dn, s_dn2);
        s_cross = fmaf(dn, ws[CSO + j], s_cross);
    }
    float ex = 0.f, sh = 0.f;
    if (t < 128) { ex = ws[PEX + t]; sh = ws[PSH + t]; }

    if (t < 16) scol[t] = 0.f;
    __syncthreads();
    {
        int d = t & 15, gq = t >> 4;
        float cs = 0.f;
        for (int m = gq; m < 128; m += 16) cs += ws[PCSD + m * 16 + d];
        atomicAdd(&scol[d], cs);
    }
    float a = waveReduce(s_dn2), c = waveReduce(s_cross);
    float e = waveReduce(ex),  s = waveReduce(sh);
    if ((t & 63) == 0) {
        int w = t >> 6;
        red[w] = a; red[4 + w] = c; red[8 + w] = e; red[12 + w] = s;
    }
    __syncthreads();
    if (t == 0) {
        float dn2   = red[0] + red[1] + red[2] + red[3];
        float cross = red[4] + red[5] + red[6] + red[7];
        float lossExceed = red[8] + red[9] + red[10] + red[11];
        float lossShape  = red[12] + red[13] + red[14] + red[15];
        float ld2 = sum_o2 / (no * no) - (2.0f / no) * cross + (float)NN * dn2;
        float lossDistance = sqrtf(fmaxf(ld2, 0.f));
        float lossPositive = 0.f;
        #pragma unroll
        for (int d = 0; d < 16; d++)
            lossPositive += fmaxf(pR[d] - scol[d], 0.f);
        out[0] = lossDistance + lossShape + lossExceed + ws[SC + 2] + lossPositive;
    }
}

extern "C" void kernel_launch(void* const* d_in, const int* in_sizes, int n_in,
                              void* d_out, int out_size, void* d_ws, size_t ws_size,
                              hipStream_t stream) {
    const int*   idx   = (const int*)d_in[0];
    const float* omega = (const float*)d_in[1];
    // d_in[2] = epoch (unused)
    const float* chL   = (const float*)d_in[3];
    const float* chH   = (const float*)d_in[4];
    const float* pL    = (const float*)d_in[5];
    const float* pH    = (const float*)d_in[6];
    const float* pR    = (const float*)d_in[7];
    const float* lr    = (const float*)d_in[8];
    float* ws  = (float*)d_ws;
    float* out = (float*)d_out;

    k_setup<<<dim3(128), 256, 0, stream>>>(idx, omega, chL, chH, pL, pH, pR, lr, ws);
    k_box<<<dim3(512), 256, 0, stream>>>(ws);
    k_gram<<<dim3(1024), 256, 0, stream>>>(ws);
    k_final<<<1, 256, 0, stream>>>(pR, ws, out);
}